// Round 7
// baseline (84.084 us; speedup 1.0000x reference)
//
#include <hip/hip_runtime.h>
#include <stdint.h>

// AggFeatureModel, two-pass:
//  pass1 (packk): coalesced repack amount->bf16(RNE) halfwords, mcc/tr->bytes
//                 into d_ws (each load-inst serves 64 lanes of unique data).
//  pass2 (agg2d_pk): 2D-factored one-hot MFMA as r6, but only 2 vector-mem
//                 instructions per 16-real step (dwordx4 bf16 + dwordx2 keys)
//                 instead of 4 -- attacks the TA instruction-issue bound.
// Fallback: if ws_size < 4*B*T bytes, run the proven r6 single-pass kernel.

#define NCOL 456
static constexpr float EPS = 1e-9f;

typedef __bf16 bf16x8 __attribute__((ext_vector_type(8)));
typedef float  f32x4  __attribute__((ext_vector_type(4)));
typedef unsigned int u32x4 __attribute__((ext_vector_type(4)));
typedef short  s16x2  __attribute__((ext_vector_type(2)));

__device__ __forceinline__ uint32_t hw_eqmask(uint32_t h) {
    // h: two halfwords, each < 0x8000; returns 0xFFFF per halfword iff h==0.
    const uint32_t s = 0x80008000u - h;                  // sign set iff halfword==0
    const s16x2 m = __builtin_bit_cast(s16x2, s) >> 15;  // packed ashr (r6-proven)
    return __builtin_bit_cast(uint32_t, m);
}

__device__ __forceinline__ uint32_t rne_bf16(uint32_t u) {
    // top 16 bits = bf16 RNE of the float bit-pattern u
    return (u + 0x7fffu + ((u >> 16) & 1u)) & 0xffff0000u;
}

// ---------------- pass 1: coalesced pack ----------------
__global__ __launch_bounds__(256) void packk(
    const float4* __restrict__ a4,
    const int4* __restrict__ m4,
    const int4* __restrict__ t4,
    uint2* __restrict__ amtH,      // bf16 pairs
    uint32_t* __restrict__ mccB,   // 4 key bytes
    uint32_t* __restrict__ trB)
{
    const size_t i = (size_t)blockIdx.x * 256 + threadIdx.x;
    const float4 a = a4[i];
    const int4   m = m4[i];
    const int4   t = t4[i];

    uint2 ah;
    ah.x = (rne_bf16(__float_as_uint(a.x)) >> 16) | rne_bf16(__float_as_uint(a.y));
    ah.y = (rne_bf16(__float_as_uint(a.z)) >> 16) | rne_bf16(__float_as_uint(a.w));
    amtH[i] = ah;
    // keys < 128: no masking needed
    mccB[i] = (uint32_t)m.x | ((uint32_t)m.y << 8) | ((uint32_t)m.z << 16) | ((uint32_t)m.w << 24);
    trB[i]  = (uint32_t)t.x | ((uint32_t)t.y << 8) | ((uint32_t)t.z << 16) | ((uint32_t)t.w << 24);
}

// ---------------- pass 2: MFMA aggregation on packed streams ----------------
__global__ __launch_bounds__(512, 8) void agg2d_pk(
    const uint16_t* __restrict__ amtH,
    const uint8_t* __restrict__ mccB,
    const uint8_t* __restrict__ trB,
    const int* __restrict__ seq_lens,
    float* __restrict__ out, int T, int B)
{
    const int lane = threadIdx.x & 63;
    const int wv   = threadIdx.x >> 6;
    const int rl   = wv >> 1;
    const int half = wv & 1;
    const int row  = blockIdx.x * 4 + rl;
    const int n    = lane & 15;
    const int grp  = lane >> 4;
    const bool istr = (grp >= 2);
    const int ntc  = istr ? ((n - 7) & 15) : n;
    const uint32_t patB = (uint32_t)(((ntc << 4) | n) * 0x01010101u);
    const int roff = (grp & 1) * 8;

    __shared__ float part[4][2][3][176];
    __shared__ float scal[4][2][2];

    const int hb = half * (T >> 1);
    const uint16_t* paH = amtH + (size_t)row * T + hb + roff;
    const uint8_t*  pkB = (istr ? trB : mccB) + (size_t)row * T + hb + roff;

    f32x4 accC = {0.f,0.f,0.f,0.f};
    f32x4 accS = {0.f,0.f,0.f,0.f};
    f32x4 accQ = {0.f,0.f,0.f,0.f};

    const int nstep = T >> 5;   // 16 reals per step over half-row
#pragma unroll 4
    for (int st = 0; st < nstep; ++st) {
        const uint4 av = *reinterpret_cast<const uint4*>(paH + (st << 4));  // 8 bf16
        const uint2 kb = *reinterpret_cast<const uint2*>(pkB + (st << 4));  // 8 key bytes

        const uint32_t kx0 = kb.x ^ patB;
        const uint32_t kx1 = kb.y ^ patB;
        // expand bytes -> duplicated-byte halfwords (self-perm: operand-order immune)
        uint32_t h[4];
        h[0] = __builtin_amdgcn_perm(kx0, kx0, 0x01010000u);
        h[1] = __builtin_amdgcn_perm(kx0, kx0, 0x03030202u);
        h[2] = __builtin_amdgcn_perm(kx1, kx1, 0x01010000u);
        h[3] = __builtin_amdgcn_perm(kx1, kx1, 0x03030202u);
        const uint32_t ap[4] = {av.x, av.y, av.z, av.w};

        u32x4 wA1, wAa, wB1, wBa;
#pragma unroll
        for (int i = 0; i < 4; ++i) {
            const uint32_t mu = hw_eqmask(h[i] & 0x000f000fu);  // u(low-nibble) match
            const uint32_t mt = hw_eqmask(h[i] & 0x00f000f0u);  // t(high-nibble) match
            wA1[i] = mt & 0x3f803f80u;
            wAa[i] = mt & ap[i];
            wB1[i] = mu & 0x3f803f80u;
            wBa[i] = mu & ap[i];
        }
        const bf16x8 fA1 = __builtin_bit_cast(bf16x8, wA1);
        const bf16x8 fAa = __builtin_bit_cast(bf16x8, wAa);
        const bf16x8 fB1 = __builtin_bit_cast(bf16x8, wB1);
        const bf16x8 fBa = __builtin_bit_cast(bf16x8, wBa);

        accC = __builtin_amdgcn_mfma_f32_16x16x32_bf16(fA1, fB1, accC, 0, 0, 0);
        accS = __builtin_amdgcn_mfma_f32_16x16x32_bf16(fA1, fBa, accS, 0, 0, 0);
        accQ = __builtin_amdgcn_mfma_f32_16x16x32_bf16(fAa, fBa, accQ, 0, 0, 0);
    }

    // ---- epilogue: identical to r6 ----
    {
        float* my = &part[rl][half][0][0];
#pragma unroll
        for (int r = 0; r < 4; ++r) {
            const int rr = grp * 4 + r;
            int addr = -1;
            if (rr <= 6)       addr = rr * 16 + n;
            else if (rr <= 10) addr = 112 + (rr - 7) * 16 + n;
            if (addr >= 0) {
                my[addr]       = accC[r];
                my[176 + addr] = accS[r];
                my[352 + addr] = accQ[r];
            }
        }
    }
    float sS = 0.f, sQ = 0.f;
    if (grp == 0) {
        sS = accS[0] + accS[1] + accS[2] + accS[3];
        sQ = accQ[0] + accQ[1] + accQ[2] + accQ[3];
    } else if (grp == 1) {
        sS = accS[0] + accS[1] + accS[2];
        sQ = accQ[0] + accQ[1] + accQ[2];
    }
#pragma unroll
    for (int off = 32; off; off >>= 1) {
        sS += __shfl_xor(sS, off, 64);
        sQ += __shfl_xor(sQ, off, 64);
    }
    if (lane == 0) { scal[rl][half][0] = sS; scal[rl][half][1] = sQ; }
    __syncthreads();

    auto TB = [&](int s, int c) -> float {
        return part[rl][0][s][c] + part[rl][1][s][c];
    };

    int dm = 0, dt = 0;
    if (half) {
        for (int c0 = 0; c0 < 160; c0 += 64) {
            const int c = c0 + lane;
            bool pos = false;
            if (c >= 1 && c < 100)        pos = TB(0, c) > 0.f;
            else if (c >= 101 && c < 150) pos = TB(0, 112 + (c - 100)) > 0.f;
            dm += __popcll(__ballot(pos && c < 100));
            dt += __popcll(__ballot(pos && c >= 100));
        }
    }

    const float sl     = (float)seq_lens[row];
    const float s_tot  = scal[rl][0][0] + scal[rl][1][0];
    const float ss_tot = scal[rl][0][1] + scal[rl][1][1];
    float* orow = out + (size_t)row * NCOL;

    for (int cc = lane; cc < 228; cc += 64) {
        const int col = half * 228 + cc;
        float v;
        if (col == 0)      v = sl;
        else if (col == 1) v = s_tot;
        else if (col == 2) v = s_tot / (sl + EPS);
        else if (col == 3) {
            float a = fmaxf(ss_tot - s_tot * s_tot / (sl + EPS), 0.f);
            v = sqrtf(a / (fmaxf(sl - 1.f, 0.f) + EPS));
        }
        else if (col == 454) v = (float)dm;
        else if (col == 455) v = (float)dt;
        else {
            int base, C, toff;
            if (col < 304) { base = 4;   C = 100; toff = 0;   }
            else           { base = 304; C = 50;  toff = 112; }
            const int rel   = col - base;
            const int which = rel / C;
            const int c     = rel - which * C;
            const float cnt = (c > 0) ? TB(0, toff + c) : 0.f;
            const float sc  = TB(1, toff + c);
            const float ssc = TB(2, toff + c);
            if (which == 0)      v = cnt;
            else if (which == 1) v = sc / (cnt + EPS);
            else {
                float a = fmaxf(ssc - sc * sc / (cnt + EPS), 0.f);
                v = sqrtf(a / (fmaxf(cnt - 1.f, 0.f) + EPS));
            }
        }
        orow[col] = v;
    }
}

// ---------------- fallback: proven r6 single-pass kernel ----------------
__global__ __launch_bounds__(512, 8) void agg2d_legacy(
    const float* __restrict__ amount,
    const int* __restrict__ mcc,
    const int* __restrict__ tr,
    const int* __restrict__ seq_lens,
    float* __restrict__ out, int T, int B)
{
    const int lane = threadIdx.x & 63;
    const int wv   = threadIdx.x >> 6;
    const int rl   = wv >> 1;
    const int half = wv & 1;
    const int row  = blockIdx.x * 4 + rl;
    const int n    = lane & 15;
    const int grp  = lane >> 4;
    const bool istr = (grp >= 2);
    const int ntc  = istr ? ((n - 7) & 15) : n;
    const uint32_t xorpat = (uint32_t)(((ntc << 4) | n) * 0x00010001u);
    const int roff = (grp & 1) * 8;

    __shared__ float part[4][2][3][176];
    __shared__ float scal[4][2][2];

    const int hb = half * (T >> 1);
    const float* pa = amount + (size_t)row * T + hb + roff;
    const int*   pk = (istr ? tr : mcc) + (size_t)row * T + hb + roff;

    f32x4 accC = {0.f,0.f,0.f,0.f};
    f32x4 accS = {0.f,0.f,0.f,0.f};
    f32x4 accQ = {0.f,0.f,0.f,0.f};

    const int nstep = T >> 5;
#pragma unroll 2
    for (int st = 0; st < nstep; ++st) {
        const int base = st << 4;
        const float4 a0 = *reinterpret_cast<const float4*>(pa + base);
        const float4 a1 = *reinterpret_cast<const float4*>(pa + base + 4);
        const int4   k0 = *reinterpret_cast<const int4*>(pk + base);
        const int4   k1 = *reinterpret_cast<const int4*>(pk + base + 4);

        const float av[8] = {a0.x,a0.y,a0.z,a0.w,a1.x,a1.y,a1.z,a1.w};
        const uint32_t kv[8] = {(uint32_t)k0.x,(uint32_t)k0.y,(uint32_t)k0.z,(uint32_t)k0.w,
                                (uint32_t)k1.x,(uint32_t)k1.y,(uint32_t)k1.z,(uint32_t)k1.w};

        u32x4 wA1, wAa, wB1, wBa;
#pragma unroll
        for (int i = 0; i < 4; ++i) {
            const uint32_t kpk = __builtin_amdgcn_perm(kv[2*i+1], kv[2*i], 0x05040100u);
            const uint32_t kx  = kpk ^ xorpat;
            const uint32_t mu  = hw_eqmask(kx & 0x000f000fu);
            const uint32_t mt  = hw_eqmask((kx >> 4) & 0x000f000fu);
            const uint32_t apk = __builtin_amdgcn_perm(
                __float_as_uint(av[2*i+1]), __float_as_uint(av[2*i]), 0x07060302u);
            wA1[i] = mt & 0x3f803f80u;
            wAa[i] = mt & apk;
            wB1[i] = mu & 0x3f803f80u;
            wBa[i] = mu & apk;
        }
        const bf16x8 fA1 = __builtin_bit_cast(bf16x8, wA1);
        const bf16x8 fAa = __builtin_bit_cast(bf16x8, wAa);
        const bf16x8 fB1 = __builtin_bit_cast(bf16x8, wB1);
        const bf16x8 fBa = __builtin_bit_cast(bf16x8, wBa);

        accC = __builtin_amdgcn_mfma_f32_16x16x32_bf16(fA1, fB1, accC, 0, 0, 0);
        accS = __builtin_amdgcn_mfma_f32_16x16x32_bf16(fA1, fBa, accS, 0, 0, 0);
        accQ = __builtin_amdgcn_mfma_f32_16x16x32_bf16(fAa, fBa, accQ, 0, 0, 0);
    }

    {
        float* my = &part[rl][half][0][0];
#pragma unroll
        for (int r = 0; r < 4; ++r) {
            const int rr = grp * 4 + r;
            int addr = -1;
            if (rr <= 6)       addr = rr * 16 + n;
            else if (rr <= 10) addr = 112 + (rr - 7) * 16 + n;
            if (addr >= 0) {
                my[addr]       = accC[r];
                my[176 + addr] = accS[r];
                my[352 + addr] = accQ[r];
            }
        }
    }
    float sS = 0.f, sQ = 0.f;
    if (grp == 0) {
        sS = accS[0] + accS[1] + accS[2] + accS[3];
        sQ = accQ[0] + accQ[1] + accQ[2] + accQ[3];
    } else if (grp == 1) {
        sS = accS[0] + accS[1] + accS[2];
        sQ = accQ[0] + accQ[1] + accQ[2];
    }
#pragma unroll
    for (int off = 32; off; off >>= 1) {
        sS += __shfl_xor(sS, off, 64);
        sQ += __shfl_xor(sQ, off, 64);
    }
    if (lane == 0) { scal[rl][half][0] = sS; scal[rl][half][1] = sQ; }
    __syncthreads();

    auto TB = [&](int s, int c) -> float {
        return part[rl][0][s][c] + part[rl][1][s][c];
    };

    int dm = 0, dt = 0;
    if (half) {
        for (int c0 = 0; c0 < 160; c0 += 64) {
            const int c = c0 + lane;
            bool pos = false;
            if (c >= 1 && c < 100)        pos = TB(0, c) > 0.f;
            else if (c >= 101 && c < 150) pos = TB(0, 112 + (c - 100)) > 0.f;
            dm += __popcll(__ballot(pos && c < 100));
            dt += __popcll(__ballot(pos && c >= 100));
        }
    }

    const float sl     = (float)seq_lens[row];
    const float s_tot  = scal[rl][0][0] + scal[rl][1][0];
    const float ss_tot = scal[rl][0][1] + scal[rl][1][1];
    float* orow = out + (size_t)row * NCOL;

    for (int cc = lane; cc < 228; cc += 64) {
        const int col = half * 228 + cc;
        float v;
        if (col == 0)      v = sl;
        else if (col == 1) v = s_tot;
        else if (col == 2) v = s_tot / (sl + EPS);
        else if (col == 3) {
            float a = fmaxf(ss_tot - s_tot * s_tot / (sl + EPS), 0.f);
            v = sqrtf(a / (fmaxf(sl - 1.f, 0.f) + EPS));
        }
        else if (col == 454) v = (float)dm;
        else if (col == 455) v = (float)dt;
        else {
            int base, C, toff;
            if (col < 304) { base = 4;   C = 100; toff = 0;   }
            else           { base = 304; C = 50;  toff = 112; }
            const int rel   = col - base;
            const int which = rel / C;
            const int c     = rel - which * C;
            const float cnt = (c > 0) ? TB(0, toff + c) : 0.f;
            const float sc  = TB(1, toff + c);
            const float ssc = TB(2, toff + c);
            if (which == 0)      v = cnt;
            else if (which == 1) v = sc / (cnt + EPS);
            else {
                float a = fmaxf(ssc - sc * sc / (cnt + EPS), 0.f);
                v = sqrtf(a / (fmaxf(cnt - 1.f, 0.f) + EPS));
            }
        }
        orow[col] = v;
    }
}

extern "C" void kernel_launch(void* const* d_in, const int* in_sizes, int n_in,
                              void* d_out, int out_size, void* d_ws, size_t ws_size,
                              hipStream_t stream) {
    const float* amount   = (const float*)d_in[0];
    const int*   mcc      = (const int*)d_in[1];
    const int*   tr_type  = (const int*)d_in[2];
    const int*   seq_lens = (const int*)d_in[3];
    float*       out      = (float*)d_out;

    const int B = in_sizes[3];            // 4096
    const int T = in_sizes[0] / B;        // 2048
    const size_t nel = (size_t)B * T;
    const size_t need = nel * 4;          // 2B bf16 + 1B mcc + 1B tr

    if (ws_size >= need) {
        uint2*    amtH = (uint2*)d_ws;                      // nel*2 bytes
        uint32_t* mccB = (uint32_t*)((char*)d_ws + nel*2);  // nel bytes
        uint32_t* trB  = (uint32_t*)((char*)d_ws + nel*3);  // nel bytes
        const int nblk = (int)(nel / 4 / 256);
        packk<<<nblk, 256, 0, stream>>>(
            (const float4*)amount, (const int4*)mcc, (const int4*)tr_type,
            amtH, mccB, trB);
        agg2d_pk<<<B / 4, 512, 0, stream>>>(
            (const uint16_t*)amtH, (const uint8_t*)mccB, (const uint8_t*)trB,
            seq_lens, out, T, B);
    } else {
        agg2d_legacy<<<B / 4, 512, 0, stream>>>(amount, mcc, tr_type, seq_lens, out, T, B);
    }
}

// Round 8
// 61.519 us; speedup vs baseline: 1.3668x; 1.3668x over previous
//
#include <hip/hip_runtime.h>
#include <stdint.h>

// AggFeatureModel, two-pass, MX-fp8 edition:
//  pass1 (packk8): coalesced repack amount->fp8 e4m3 (v_cvt_pk_fp8_f32, RNE),
//       mcc/tr->bytes, PLUS exact-f32 per-half-row {s,ss} partials into d_ws
//       (keeps the 31623x-amplified sl==1 std columns f32-exact).
//  pass2 (agg_mx): 2D-factored one-hot histogram via
//       mfma_scale_f32_16x16x128_f8f6f4 (K=128): one MFMA trio per 64
//       elements (4x fewer MFMA/loop-overhead than r7) with byte-SWAR
//       eq-masks: (0x80808080 - h) & 0x80808080 is borrow-free for
//       nibble-valued bytes. Scales = 1.0 (0x7f per byte).
// Fallback: proven r6/r7 bf16 single-pass kernel if ws too small.

#define NCOL 456
static constexpr float EPS = 1e-9f;

typedef __bf16 bf16x8 __attribute__((ext_vector_type(8)));
typedef float  f32x4  __attribute__((ext_vector_type(4)));
typedef int    i32x8  __attribute__((ext_vector_type(8)));
typedef unsigned int u32x4 __attribute__((ext_vector_type(4)));
typedef short  s16x2  __attribute__((ext_vector_type(2)));

__device__ __forceinline__ uint32_t hw_eqmask(uint32_t h) {
    // halfword SWAR eq-zero (legacy kernel)
    const uint32_t s = 0x80008000u - h;
    const s16x2 m = __builtin_bit_cast(s16x2, s) >> 15;
    return __builtin_bit_cast(uint32_t, m);
}

// ---------------- pass 1: coalesced pack + exact f32 row partials ----------------
__global__ __launch_bounds__(256) void packk8(
    const float4* __restrict__ a4,
    const int4* __restrict__ m4,
    const int4* __restrict__ t4,
    uint32_t* __restrict__ valB,   // fp8 e4m3 bytes
    uint32_t* __restrict__ mccB,   // key bytes
    uint32_t* __restrict__ trB,
    float2* __restrict__ scal)     // per half-row {s, ss}, block == half-row
{
    const int tid = threadIdx.x;
    const size_t i = (size_t)blockIdx.x * 256 + tid;
    const float4 a = a4[i];
    const int4   m = m4[i];
    const int4   t = t4[i];

    uint32_t w = __builtin_amdgcn_cvt_pk_fp8_f32(a.x, a.y, 0u, false);
    w = __builtin_amdgcn_cvt_pk_fp8_f32(a.z, a.w, w, true);
    valB[i] = w;
    mccB[i] = (uint32_t)m.x | ((uint32_t)m.y << 8) | ((uint32_t)m.z << 16) | ((uint32_t)m.w << 24);
    trB[i]  = (uint32_t)t.x | ((uint32_t)t.y << 8) | ((uint32_t)t.z << 16) | ((uint32_t)t.w << 24);

    float s = (a.x + a.y) + (a.z + a.w);
    float q = fmaf(a.x, a.x, fmaf(a.y, a.y, fmaf(a.z, a.z, a.w * a.w)));
#pragma unroll
    for (int off = 32; off; off >>= 1) {
        s += __shfl_xor(s, off, 64);
        q += __shfl_xor(q, off, 64);
    }
    __shared__ float rs[4][2];
    if ((tid & 63) == 0) { rs[tid >> 6][0] = s; rs[tid >> 6][1] = q; }
    __syncthreads();
    if (tid == 0)
        scal[blockIdx.x] = make_float2(rs[0][0] + rs[1][0] + rs[2][0] + rs[3][0],
                                       rs[0][1] + rs[1][1] + rs[2][1] + rs[3][1]);
}

// ---------------- pass 2: MX-fp8 K=128 MFMA aggregation ----------------
__global__ __launch_bounds__(512, 4) void agg_mx(
    const uint8_t* __restrict__ valB,
    const uint8_t* __restrict__ mccB,
    const uint8_t* __restrict__ trB,
    const float2* __restrict__ scal,
    const int* __restrict__ seq_lens,
    float* __restrict__ out, int T, int B)
{
    const int lane = threadIdx.x & 63;
    const int wv   = threadIdx.x >> 6;
    const int rl   = wv >> 1;
    const int half = wv & 1;
    const int row  = blockIdx.x * 4 + rl;
    const int n    = lane & 15;
    const int grp  = lane >> 4;
    const bool istr = (grp >= 2);
    const int ntc  = istr ? ((n - 7) & 15) : n;
    const uint32_t patB = (uint32_t)(((ntc << 4) | n) * 0x01010101u);

    __shared__ float part[4][2][3][176];

    // K layout: slots 0-63 = mcc-keyed elems 0-63, 64-127 = tr-keyed same elems.
    // lane(grp): bytes k = 32*grp + j -> grp0/1: mcc elems 0-31/32-63; grp2/3: tr same.
    const size_t rb = (size_t)row * T + half * (T >> 1) + ((grp & 1) << 5);
    const uint8_t* pv = valB + rb;
    const uint8_t* pk = (istr ? trB : mccB) + rb;

    f32x4 accC = {0.f,0.f,0.f,0.f};
    f32x4 accS = {0.f,0.f,0.f,0.f};
    f32x4 accQ = {0.f,0.f,0.f,0.f};

    const int nstep = T >> 7;   // 64 elems/step over half-row
#pragma unroll 2
    for (int st = 0; st < nstep; ++st) {
        const int off = st << 6;
        const uint4 v0 = *reinterpret_cast<const uint4*>(pv + off);
        const uint4 v1 = *reinterpret_cast<const uint4*>(pv + off + 16);
        const uint4 k0 = *reinterpret_cast<const uint4*>(pk + off);
        const uint4 k1 = *reinterpret_cast<const uint4*>(pk + off + 16);

        i32x8 fA1, fAa, fB1, fBa;
#define DOW(j, kw, vw) { \
        const uint32_t kx = (kw) ^ patB; \
        const uint32_t hu = kx & 0x0f0f0f0fu; \
        const uint32_t mu = (((0x80808080u - hu) & 0x80808080u) >> 7) * 255u; \
        const uint32_t ht = (kx >> 4) & 0x0f0f0f0fu; \
        const uint32_t mt = (((0x80808080u - ht) & 0x80808080u) >> 7) * 255u; \
        fA1[j] = (int)(mt & 0x38383838u);  /* one-hot(t) * 1.0 (e4m3) */ \
        fAa[j] = (int)(mt & (vw)); \
        fB1[j] = (int)(mu & 0x38383838u); \
        fBa[j] = (int)(mu & (vw)); }
        DOW(0, k0.x, v0.x) DOW(1, k0.y, v0.y) DOW(2, k0.z, v0.z) DOW(3, k0.w, v0.w)
        DOW(4, k1.x, v1.x) DOW(5, k1.y, v1.y) DOW(6, k1.z, v1.z) DOW(7, k1.w, v1.w)
#undef DOW

        accC = __builtin_amdgcn_mfma_scale_f32_16x16x128_f8f6f4(
                   fA1, fB1, accC, 0, 0, 0, 0x7f7f7f7f, 0, 0x7f7f7f7f);
        accS = __builtin_amdgcn_mfma_scale_f32_16x16x128_f8f6f4(
                   fA1, fBa, accS, 0, 0, 0, 0x7f7f7f7f, 0, 0x7f7f7f7f);
        accQ = __builtin_amdgcn_mfma_scale_f32_16x16x128_f8f6f4(
                   fAa, fBa, accQ, 0, 0, 0, 0x7f7f7f7f, 0, 0x7f7f7f7f);
    }

    // ---- epilogue: D layout col = lane&15, row = grp*4 + reg (r7-proven) ----
    {
        float* my = &part[rl][half][0][0];
#pragma unroll
        for (int r = 0; r < 4; ++r) {
            const int rr = grp * 4 + r;
            int addr = -1;
            if (rr <= 6)       addr = rr * 16 + n;
            else if (rr <= 10) addr = 112 + (rr - 7) * 16 + n;
            if (addr >= 0) {
                my[addr]       = accC[r];
                my[176 + addr] = accS[r];
                my[352 + addr] = accQ[r];
            }
        }
    }
    __syncthreads();

    auto TB = [&](int s, int c) -> float {
        return part[rl][0][s][c] + part[rl][1][s][c];
    };

    int dm = 0, dt = 0;
    if (half) {
        for (int c0 = 0; c0 < 160; c0 += 64) {
            const int c = c0 + lane;
            bool pos = false;
            if (c >= 1 && c < 100)        pos = TB(0, c) > 0.f;
            else if (c >= 101 && c < 150) pos = TB(0, 112 + (c - 100)) > 0.f;
            dm += __popcll(__ballot(pos && c < 100));
            dt += __popcll(__ballot(pos && c >= 100));
        }
    }

    const float2 sc0 = scal[2 * row];
    const float2 sc1 = scal[2 * row + 1];
    const float s_tot  = sc0.x + sc1.x;
    const float ss_tot = sc0.y + sc1.y;
    const float sl = (float)seq_lens[row];
    float* orow = out + (size_t)row * NCOL;

    for (int cc = lane; cc < 228; cc += 64) {
        const int col = half * 228 + cc;
        float v;
        if (col == 0)      v = sl;
        else if (col == 1) v = s_tot;
        else if (col == 2) v = s_tot / (sl + EPS);
        else if (col == 3) {
            float a = fmaxf(ss_tot - s_tot * s_tot / (sl + EPS), 0.f);
            v = sqrtf(a / (fmaxf(sl - 1.f, 0.f) + EPS));
        }
        else if (col == 454) v = (float)dm;
        else if (col == 455) v = (float)dt;
        else {
            int base, C, toff;
            if (col < 304) { base = 4;   C = 100; toff = 0;   }
            else           { base = 304; C = 50;  toff = 112; }
            const int rel   = col - base;
            const int which = rel / C;
            const int c     = rel - which * C;
            const float cnt = (c > 0) ? TB(0, toff + c) : 0.f;
            const float sc  = TB(1, toff + c);
            const float ssc = TB(2, toff + c);
            if (which == 0)      v = cnt;
            else if (which == 1) v = sc / (cnt + EPS);
            else {
                float a = fmaxf(ssc - sc * sc / (cnt + EPS), 0.f);
                v = sqrtf(a / (fmaxf(cnt - 1.f, 0.f) + EPS));
            }
        }
        orow[col] = v;
    }
}

// ---------------- fallback: proven r6 single-pass bf16 kernel ----------------
__global__ __launch_bounds__(512, 8) void agg2d_legacy(
    const float* __restrict__ amount,
    const int* __restrict__ mcc,
    const int* __restrict__ tr,
    const int* __restrict__ seq_lens,
    float* __restrict__ out, int T, int B)
{
    const int lane = threadIdx.x & 63;
    const int wv   = threadIdx.x >> 6;
    const int rl   = wv >> 1;
    const int half = wv & 1;
    const int row  = blockIdx.x * 4 + rl;
    const int n    = lane & 15;
    const int grp  = lane >> 4;
    const bool istr = (grp >= 2);
    const int ntc  = istr ? ((n - 7) & 15) : n;
    const uint32_t xorpat = (uint32_t)(((ntc << 4) | n) * 0x00010001u);
    const int roff = (grp & 1) * 8;

    __shared__ float part[4][2][3][176];
    __shared__ float scal[4][2][2];

    const int hb = half * (T >> 1);
    const float* pa = amount + (size_t)row * T + hb + roff;
    const int*   pk = (istr ? tr : mcc) + (size_t)row * T + hb + roff;

    f32x4 accC = {0.f,0.f,0.f,0.f};
    f32x4 accS = {0.f,0.f,0.f,0.f};
    f32x4 accQ = {0.f,0.f,0.f,0.f};

    const int nstep = T >> 5;
#pragma unroll 2
    for (int st = 0; st < nstep; ++st) {
        const int base = st << 4;
        const float4 a0 = *reinterpret_cast<const float4*>(pa + base);
        const float4 a1 = *reinterpret_cast<const float4*>(pa + base + 4);
        const int4   k0 = *reinterpret_cast<const int4*>(pk + base);
        const int4   k1 = *reinterpret_cast<const int4*>(pk + base + 4);

        const float av[8] = {a0.x,a0.y,a0.z,a0.w,a1.x,a1.y,a1.z,a1.w};
        const uint32_t kv[8] = {(uint32_t)k0.x,(uint32_t)k0.y,(uint32_t)k0.z,(uint32_t)k0.w,
                                (uint32_t)k1.x,(uint32_t)k1.y,(uint32_t)k1.z,(uint32_t)k1.w};

        u32x4 wA1, wAa, wB1, wBa;
#pragma unroll
        for (int i = 0; i < 4; ++i) {
            const uint32_t kpk = __builtin_amdgcn_perm(kv[2*i+1], kv[2*i], 0x05040100u);
            const uint32_t kx  = kpk ^ xorpat;
            const uint32_t mu  = hw_eqmask(kx & 0x000f000fu);
            const uint32_t mt  = hw_eqmask((kx >> 4) & 0x000f000fu);
            const uint32_t apk = __builtin_amdgcn_perm(
                __float_as_uint(av[2*i+1]), __float_as_uint(av[2*i]), 0x07060302u);
            wA1[i] = mt & 0x3f803f80u;
            wAa[i] = mt & apk;
            wB1[i] = mu & 0x3f803f80u;
            wBa[i] = mu & apk;
        }
        const bf16x8 fA1 = __builtin_bit_cast(bf16x8, wA1);
        const bf16x8 fAa = __builtin_bit_cast(bf16x8, wAa);
        const bf16x8 fB1 = __builtin_bit_cast(bf16x8, wB1);
        const bf16x8 fBa = __builtin_bit_cast(bf16x8, wBa);

        accC = __builtin_amdgcn_mfma_f32_16x16x32_bf16(fA1, fB1, accC, 0, 0, 0);
        accS = __builtin_amdgcn_mfma_f32_16x16x32_bf16(fA1, fBa, accS, 0, 0, 0);
        accQ = __builtin_amdgcn_mfma_f32_16x16x32_bf16(fAa, fBa, accQ, 0, 0, 0);
    }

    {
        float* my = &part[rl][half][0][0];
#pragma unroll
        for (int r = 0; r < 4; ++r) {
            const int rr = grp * 4 + r;
            int addr = -1;
            if (rr <= 6)       addr = rr * 16 + n;
            else if (rr <= 10) addr = 112 + (rr - 7) * 16 + n;
            if (addr >= 0) {
                my[addr]       = accC[r];
                my[176 + addr] = accS[r];
                my[352 + addr] = accQ[r];
            }
        }
    }
    float sS = 0.f, sQ = 0.f;
    if (grp == 0) {
        sS = accS[0] + accS[1] + accS[2] + accS[3];
        sQ = accQ[0] + accQ[1] + accQ[2] + accQ[3];
    } else if (grp == 1) {
        sS = accS[0] + accS[1] + accS[2];
        sQ = accQ[0] + accQ[1] + accQ[2];
    }
#pragma unroll
    for (int off = 32; off; off >>= 1) {
        sS += __shfl_xor(sS, off, 64);
        sQ += __shfl_xor(sQ, off, 64);
    }
    if (lane == 0) { scal[rl][half][0] = sS; scal[rl][half][1] = sQ; }
    __syncthreads();

    auto TB = [&](int s, int c) -> float {
        return part[rl][0][s][c] + part[rl][1][s][c];
    };

    int dm = 0, dt = 0;
    if (half) {
        for (int c0 = 0; c0 < 160; c0 += 64) {
            const int c = c0 + lane;
            bool pos = false;
            if (c >= 1 && c < 100)        pos = TB(0, c) > 0.f;
            else if (c >= 101 && c < 150) pos = TB(0, 112 + (c - 100)) > 0.f;
            dm += __popcll(__ballot(pos && c < 100));
            dt += __popcll(__ballot(pos && c >= 100));
        }
    }

    const float sl     = (float)seq_lens[row];
    const float s_tot  = scal[rl][0][0] + scal[rl][1][0];
    const float ss_tot = scal[rl][0][1] + scal[rl][1][1];
    float* orow = out + (size_t)row * NCOL;

    for (int cc = lane; cc < 228; cc += 64) {
        const int col = half * 228 + cc;
        float v;
        if (col == 0)      v = sl;
        else if (col == 1) v = s_tot;
        else if (col == 2) v = s_tot / (sl + EPS);
        else if (col == 3) {
            float a = fmaxf(ss_tot - s_tot * s_tot / (sl + EPS), 0.f);
            v = sqrtf(a / (fmaxf(sl - 1.f, 0.f) + EPS));
        }
        else if (col == 454) v = (float)dm;
        else if (col == 455) v = (float)dt;
        else {
            int base, C, toff;
            if (col < 304) { base = 4;   C = 100; toff = 0;   }
            else           { base = 304; C = 50;  toff = 112; }
            const int rel   = col - base;
            const int which = rel / C;
            const int c     = rel - which * C;
            const float cnt = (c > 0) ? TB(0, toff + c) : 0.f;
            const float sc  = TB(1, toff + c);
            const float ssc = TB(2, toff + c);
            if (which == 0)      v = cnt;
            else if (which == 1) v = sc / (cnt + EPS);
            else {
                float a = fmaxf(ssc - sc * sc / (cnt + EPS), 0.f);
                v = sqrtf(a / (fmaxf(cnt - 1.f, 0.f) + EPS));
            }
        }
        orow[col] = v;
    }
}

extern "C" void kernel_launch(void* const* d_in, const int* in_sizes, int n_in,
                              void* d_out, int out_size, void* d_ws, size_t ws_size,
                              hipStream_t stream) {
    const float* amount   = (const float*)d_in[0];
    const int*   mcc      = (const int*)d_in[1];
    const int*   tr_type  = (const int*)d_in[2];
    const int*   seq_lens = (const int*)d_in[3];
    float*       out      = (float*)d_out;

    const int B = in_sizes[3];            // 4096
    const int T = in_sizes[0] / B;        // 2048
    const size_t nel = (size_t)B * T;
    const size_t nhalf = nel / 1024;      // half-rows (pack block = 1024 elems)
    const size_t need = nel * 3 + nhalf * sizeof(float2);

    if (ws_size >= need && (T % 2048) == 0) {
        uint32_t* valB = (uint32_t*)d_ws;
        uint32_t* mccB = (uint32_t*)((char*)d_ws + nel);
        uint32_t* trB  = (uint32_t*)((char*)d_ws + 2 * nel);
        float2*   scal = (float2*)((char*)d_ws + 3 * nel);
        packk8<<<(int)nhalf, 256, 0, stream>>>(
            (const float4*)amount, (const int4*)mcc, (const int4*)tr_type,
            valB, mccB, trB, scal);
        agg_mx<<<B / 4, 512, 0, stream>>>(
            (const uint8_t*)valB, (const uint8_t*)mccB, (const uint8_t*)trB,
            scal, seq_lens, out, T, B);
    } else {
        agg2d_legacy<<<B / 4, 512, 0, stream>>>(amount, mcc, tr_type, seq_lens, out, T, B);
    }
}

// Round 9
// 51.976 us; speedup vs baseline: 1.6178x; 1.1836x over previous
//
#include <hip/hip_runtime.h>
#include <stdint.h>

// AggFeatureModel, FUSED single-pass (T==2048 path):
//  phase A: block stages its 4 rows coalesced (4 rounds of 512 x {float4,
//      int4, int4} = one full row per round), converts amount->fp8 e4m3
//      (v_cvt_pk_fp8_f32) and keys->bytes in registers, writes 24 KB of
//      packed LDS, and wave-reduces exact-f32 {s,ss} partials per row.
//  phase B: r8-proven 2D-factored one-hot histogram via
//      mfma_scale_f32_16x16x128_f8f6f4 (K=128), operands built with
//      byte-SWAR eq-masks, reading packed bytes from LDS (16-lane
//      same-address reads broadcast, conflict-free).
//  Fusion overlaps the ~100MB HBM read (was a serial 19us pack pass) with
//  the VALU-bound MFMA phase across resident blocks; kills the 33.6MB
//  intermediate round-trip and one dispatch. d_ws unused.
// Fallback: proven r6 bf16 single-pass kernel for T != 2048.

#define NCOL 456
static constexpr float EPS = 1e-9f;

typedef __bf16 bf16x8 __attribute__((ext_vector_type(8)));
typedef float  f32x4  __attribute__((ext_vector_type(4)));
typedef int    i32x8  __attribute__((ext_vector_type(8)));
typedef unsigned int u32x4 __attribute__((ext_vector_type(4)));
typedef short  s16x2  __attribute__((ext_vector_type(2)));

__device__ __forceinline__ uint32_t hw_eqmask(uint32_t h) {
    // halfword SWAR eq-zero (legacy kernel)
    const uint32_t s = 0x80008000u - h;
    const s16x2 m = __builtin_bit_cast(s16x2, s) >> 15;
    return __builtin_bit_cast(uint32_t, m);
}

// ---------------- fused kernel (T == 2048) ----------------
__global__ __launch_bounds__(512, 4) void agg_fused(
    const float4* __restrict__ a4,
    const int4* __restrict__ m4,
    const int4* __restrict__ t4,
    const int* __restrict__ seq_lens,
    float* __restrict__ out, int B)
{
    const int tid  = threadIdx.x;
    const int lane = tid & 63;
    const int wv   = tid >> 6;           // 0..7

    __shared__ uint32_t lv[2048];        // fp8 bytes, 4 rows x 2048
    __shared__ uint32_t lm[2048];        // mcc key bytes
    __shared__ uint32_t lt[2048];        // tr key bytes
    __shared__ float part[4][2][3][176];
    __shared__ float scw[4][8][2];       // [row][wave]{s,ss}

    // ---- phase A: stage + convert + exact f32 row partials ----
    const size_t base4 = (size_t)blockIdx.x * 2048;   // float4 units
#pragma unroll
    for (int j = 0; j < 4; ++j) {        // round j == local row j
        const size_t gi = base4 + (size_t)j * 512 + tid;
        const float4 a = a4[gi];
        const int4   m = m4[gi];
        const int4   t = t4[gi];

        uint32_t w = __builtin_amdgcn_cvt_pk_fp8_f32(a.x, a.y, 0u, false);
        w = __builtin_amdgcn_cvt_pk_fp8_f32(a.z, a.w, w, true);
        lv[j * 512 + tid] = w;
        lm[j * 512 + tid] = (uint32_t)m.x | ((uint32_t)m.y << 8)
                          | ((uint32_t)m.z << 16) | ((uint32_t)m.w << 24);
        lt[j * 512 + tid] = (uint32_t)t.x | ((uint32_t)t.y << 8)
                          | ((uint32_t)t.z << 16) | ((uint32_t)t.w << 24);

        float s = (a.x + a.y) + (a.z + a.w);
        float q = fmaf(a.x, a.x, fmaf(a.y, a.y, fmaf(a.z, a.z, a.w * a.w)));
#pragma unroll
        for (int off = 32; off; off >>= 1) {
            s += __shfl_xor(s, off, 64);
            q += __shfl_xor(q, off, 64);
        }
        if (lane == 0) { scw[j][wv][0] = s; scw[j][wv][1] = q; }
    }
    __syncthreads();

    // ---- phase B: MX-fp8 K=128 MFMA histogram from LDS ----
    const int rl   = wv >> 1;            // local row
    const int half = wv & 1;             // half of T axis
    const int row  = blockIdx.x * 4 + rl;
    const int n    = lane & 15;
    const int grp  = lane >> 4;
    const bool istr = (grp >= 2);
    const int ntc  = istr ? ((n - 7) & 15) : n;
    const uint32_t patB = (uint32_t)(((ntc << 4) | n) * 0x01010101u);

    const int bb = rl * 2048 + half * 1024 + ((grp & 1) << 5);
    const uint8_t* pv = (const uint8_t*)lv + bb;
    const uint8_t* pk = (const uint8_t*)(istr ? lt : lm) + bb;

    f32x4 accC = {0.f,0.f,0.f,0.f};
    f32x4 accS = {0.f,0.f,0.f,0.f};
    f32x4 accQ = {0.f,0.f,0.f,0.f};

#pragma unroll 2
    for (int st = 0; st < 16; ++st) {    // 64 elems/step over half-row
        const int off = st << 6;
        const uint4 v0 = *reinterpret_cast<const uint4*>(pv + off);
        const uint4 v1 = *reinterpret_cast<const uint4*>(pv + off + 16);
        const uint4 k0 = *reinterpret_cast<const uint4*>(pk + off);
        const uint4 k1 = *reinterpret_cast<const uint4*>(pk + off + 16);

        i32x8 fA1, fAa, fB1, fBa;
#define DOW(j, kw, vw) { \
        const uint32_t kx = (kw) ^ patB; \
        const uint32_t hu = kx & 0x0f0f0f0fu; \
        const uint32_t mu = (((0x80808080u - hu) & 0x80808080u) >> 7) * 255u; \
        const uint32_t ht = (kx >> 4) & 0x0f0f0f0fu; \
        const uint32_t mt = (((0x80808080u - ht) & 0x80808080u) >> 7) * 255u; \
        fA1[j] = (int)(mt & 0x38383838u);  /* one-hot(t) * 1.0 (e4m3) */ \
        fAa[j] = (int)(mt & (vw)); \
        fB1[j] = (int)(mu & 0x38383838u); \
        fBa[j] = (int)(mu & (vw)); }
        DOW(0, k0.x, v0.x) DOW(1, k0.y, v0.y) DOW(2, k0.z, v0.z) DOW(3, k0.w, v0.w)
        DOW(4, k1.x, v1.x) DOW(5, k1.y, v1.y) DOW(6, k1.z, v1.z) DOW(7, k1.w, v1.w)
#undef DOW

        accC = __builtin_amdgcn_mfma_scale_f32_16x16x128_f8f6f4(
                   fA1, fB1, accC, 0, 0, 0, 0x7f7f7f7f, 0, 0x7f7f7f7f);
        accS = __builtin_amdgcn_mfma_scale_f32_16x16x128_f8f6f4(
                   fA1, fBa, accS, 0, 0, 0, 0x7f7f7f7f, 0, 0x7f7f7f7f);
        accQ = __builtin_amdgcn_mfma_scale_f32_16x16x128_f8f6f4(
                   fAa, fBa, accQ, 0, 0, 0, 0x7f7f7f7f, 0, 0x7f7f7f7f);
    }

    // ---- epilogue: D layout col = lane&15, row = grp*4 + reg (r8-proven) ----
    {
        float* my = &part[rl][half][0][0];
#pragma unroll
        for (int r = 0; r < 4; ++r) {
            const int rr = grp * 4 + r;
            int addr = -1;
            if (rr <= 6)       addr = rr * 16 + n;
            else if (rr <= 10) addr = 112 + (rr - 7) * 16 + n;
            if (addr >= 0) {
                my[addr]       = accC[r];
                my[176 + addr] = accS[r];
                my[352 + addr] = accQ[r];
            }
        }
    }
    __syncthreads();

    auto TB = [&](int s, int c) -> float {
        return part[rl][0][s][c] + part[rl][1][s][c];
    };

    int dm = 0, dt = 0;
    if (half) {
        for (int c0 = 0; c0 < 160; c0 += 64) {
            const int c = c0 + lane;
            bool pos = false;
            if (c >= 1 && c < 100)        pos = TB(0, c) > 0.f;
            else if (c >= 101 && c < 150) pos = TB(0, 112 + (c - 100)) > 0.f;
            dm += __popcll(__ballot(pos && c < 100));
            dt += __popcll(__ballot(pos && c >= 100));
        }
    }

    float s_tot = 0.f, ss_tot = 0.f;
#pragma unroll
    for (int w = 0; w < 8; ++w) {
        s_tot  += scw[rl][w][0];
        ss_tot += scw[rl][w][1];
    }
    const float sl = (float)seq_lens[row];
    float* orow = out + (size_t)row * NCOL;

    for (int cc = lane; cc < 228; cc += 64) {
        const int col = half * 228 + cc;
        float v;
        if (col == 0)      v = sl;
        else if (col == 1) v = s_tot;
        else if (col == 2) v = s_tot / (sl + EPS);
        else if (col == 3) {
            float a = fmaxf(ss_tot - s_tot * s_tot / (sl + EPS), 0.f);
            v = sqrtf(a / (fmaxf(sl - 1.f, 0.f) + EPS));
        }
        else if (col == 454) v = (float)dm;
        else if (col == 455) v = (float)dt;
        else {
            int base, C, toff;
            if (col < 304) { base = 4;   C = 100; toff = 0;   }
            else           { base = 304; C = 50;  toff = 112; }
            const int rel   = col - base;
            const int which = rel / C;
            const int c     = rel - which * C;
            const float cnt = (c > 0) ? TB(0, toff + c) : 0.f;
            const float sc  = TB(1, toff + c);
            const float ssc = TB(2, toff + c);
            if (which == 0)      v = cnt;
            else if (which == 1) v = sc / (cnt + EPS);
            else {
                float a = fmaxf(ssc - sc * sc / (cnt + EPS), 0.f);
                v = sqrtf(a / (fmaxf(cnt - 1.f, 0.f) + EPS));
            }
        }
        orow[col] = v;
    }
}

// ---------------- fallback: proven r6 single-pass bf16 kernel ----------------
__global__ __launch_bounds__(512, 8) void agg2d_legacy(
    const float* __restrict__ amount,
    const int* __restrict__ mcc,
    const int* __restrict__ tr,
    const int* __restrict__ seq_lens,
    float* __restrict__ out, int T, int B)
{
    const int lane = threadIdx.x & 63;
    const int wv   = threadIdx.x >> 6;
    const int rl   = wv >> 1;
    const int half = wv & 1;
    const int row  = blockIdx.x * 4 + rl;
    const int n    = lane & 15;
    const int grp  = lane >> 4;
    const bool istr = (grp >= 2);
    const int ntc  = istr ? ((n - 7) & 15) : n;
    const uint32_t xorpat = (uint32_t)(((ntc << 4) | n) * 0x00010001u);
    const int roff = (grp & 1) * 8;

    __shared__ float part[4][2][3][176];
    __shared__ float scal[4][2][2];

    const int hb = half * (T >> 1);
    const float* pa = amount + (size_t)row * T + hb + roff;
    const int*   pk = (istr ? tr : mcc) + (size_t)row * T + hb + roff;

    f32x4 accC = {0.f,0.f,0.f,0.f};
    f32x4 accS = {0.f,0.f,0.f,0.f};
    f32x4 accQ = {0.f,0.f,0.f,0.f};

    const int nstep = T >> 5;
#pragma unroll 2
    for (int st = 0; st < nstep; ++st) {
        const int base = st << 4;
        const float4 a0 = *reinterpret_cast<const float4*>(pa + base);
        const float4 a1 = *reinterpret_cast<const float4*>(pa + base + 4);
        const int4   k0 = *reinterpret_cast<const int4*>(pk + base);
        const int4   k1 = *reinterpret_cast<const int4*>(pk + base + 4);

        const float av[8] = {a0.x,a0.y,a0.z,a0.w,a1.x,a1.y,a1.z,a1.w};
        const uint32_t kv[8] = {(uint32_t)k0.x,(uint32_t)k0.y,(uint32_t)k0.z,(uint32_t)k0.w,
                                (uint32_t)k1.x,(uint32_t)k1.y,(uint32_t)k1.z,(uint32_t)k1.w};

        u32x4 wA1, wAa, wB1, wBa;
#pragma unroll
        for (int i = 0; i < 4; ++i) {
            const uint32_t kpk = __builtin_amdgcn_perm(kv[2*i+1], kv[2*i], 0x05040100u);
            const uint32_t kx  = kpk ^ xorpat;
            const uint32_t mu  = hw_eqmask(kx & 0x000f000fu);
            const uint32_t mt  = hw_eqmask((kx >> 4) & 0x000f000fu);
            const uint32_t apk = __builtin_amdgcn_perm(
                __float_as_uint(av[2*i+1]), __float_as_uint(av[2*i]), 0x07060302u);
            wA1[i] = mt & 0x3f803f80u;
            wAa[i] = mt & apk;
            wB1[i] = mu & 0x3f803f80u;
            wBa[i] = mu & apk;
        }
        const bf16x8 fA1 = __builtin_bit_cast(bf16x8, wA1);
        const bf16x8 fAa = __builtin_bit_cast(bf16x8, wAa);
        const bf16x8 fB1 = __builtin_bit_cast(bf16x8, wB1);
        const bf16x8 fBa = __builtin_bit_cast(bf16x8, wBa);

        accC = __builtin_amdgcn_mfma_f32_16x16x32_bf16(fA1, fB1, accC, 0, 0, 0);
        accS = __builtin_amdgcn_mfma_f32_16x16x32_bf16(fA1, fBa, accS, 0, 0, 0);
        accQ = __builtin_amdgcn_mfma_f32_16x16x32_bf16(fAa, fBa, accQ, 0, 0, 0);
    }

    {
        float* my = &part[rl][half][0][0];
#pragma unroll
        for (int r = 0; r < 4; ++r) {
            const int rr = grp * 4 + r;
            int addr = -1;
            if (rr <= 6)       addr = rr * 16 + n;
            else if (rr <= 10) addr = 112 + (rr - 7) * 16 + n;
            if (addr >= 0) {
                my[addr]       = accC[r];
                my[176 + addr] = accS[r];
                my[352 + addr] = accQ[r];
            }
        }
    }
    float sS = 0.f, sQ = 0.f;
    if (grp == 0) {
        sS = accS[0] + accS[1] + accS[2] + accS[3];
        sQ = accQ[0] + accQ[1] + accQ[2] + accQ[3];
    } else if (grp == 1) {
        sS = accS[0] + accS[1] + accS[2];
        sQ = accQ[0] + accQ[1] + accQ[2];
    }
#pragma unroll
    for (int off = 32; off; off >>= 1) {
        sS += __shfl_xor(sS, off, 64);
        sQ += __shfl_xor(sQ, off, 64);
    }
    if (lane == 0) { scal[rl][half][0] = sS; scal[rl][half][1] = sQ; }
    __syncthreads();

    auto TB = [&](int s, int c) -> float {
        return part[rl][0][s][c] + part[rl][1][s][c];
    };

    int dm = 0, dt = 0;
    if (half) {
        for (int c0 = 0; c0 < 160; c0 += 64) {
            const int c = c0 + lane;
            bool pos = false;
            if (c >= 1 && c < 100)        pos = TB(0, c) > 0.f;
            else if (c >= 101 && c < 150) pos = TB(0, 112 + (c - 100)) > 0.f;
            dm += __popcll(__ballot(pos && c < 100));
            dt += __popcll(__ballot(pos && c >= 100));
        }
    }

    const float sl     = (float)seq_lens[row];
    const float s_tot  = scal[rl][0][0] + scal[rl][1][0];
    const float ss_tot = scal[rl][0][1] + scal[rl][1][1];
    float* orow = out + (size_t)row * NCOL;

    for (int cc = lane; cc < 228; cc += 64) {
        const int col = half * 228 + cc;
        float v;
        if (col == 0)      v = sl;
        else if (col == 1) v = s_tot;
        else if (col == 2) v = s_tot / (sl + EPS);
        else if (col == 3) {
            float a = fmaxf(ss_tot - s_tot * s_tot / (sl + EPS), 0.f);
            v = sqrtf(a / (fmaxf(sl - 1.f, 0.f) + EPS));
        }
        else if (col == 454) v = (float)dm;
        else if (col == 455) v = (float)dt;
        else {
            int base, C, toff;
            if (col < 304) { base = 4;   C = 100; toff = 0;   }
            else           { base = 304; C = 50;  toff = 112; }
            const int rel   = col - base;
            const int which = rel / C;
            const int c     = rel - which * C;
            const float cnt = (c > 0) ? TB(0, toff + c) : 0.f;
            const float sc  = TB(1, toff + c);
            const float ssc = TB(2, toff + c);
            if (which == 0)      v = cnt;
            else if (which == 1) v = sc / (cnt + EPS);
            else {
                float a = fmaxf(ssc - sc * sc / (cnt + EPS), 0.f);
                v = sqrtf(a / (fmaxf(cnt - 1.f, 0.f) + EPS));
            }
        }
        orow[col] = v;
    }
}

extern "C" void kernel_launch(void* const* d_in, const int* in_sizes, int n_in,
                              void* d_out, int out_size, void* d_ws, size_t ws_size,
                              hipStream_t stream) {
    const float* amount   = (const float*)d_in[0];
    const int*   mcc      = (const int*)d_in[1];
    const int*   tr_type  = (const int*)d_in[2];
    const int*   seq_lens = (const int*)d_in[3];
    float*       out      = (float*)d_out;

    const int B = in_sizes[3];            // 4096
    const int T = in_sizes[0] / B;        // 2048

    if (T == 2048 && (B % 4) == 0) {
        agg_fused<<<B / 4, 512, 0, stream>>>(
            (const float4*)amount, (const int4*)mcc, (const int4*)tr_type,
            seq_lens, out, B);
    } else {
        agg2d_legacy<<<B / 4, 512, 0, stream>>>(amount, mcc, tr_type, seq_lens, out, T, B);
    }
}

// Round 10
// 51.026 us; speedup vs baseline: 1.6479x; 1.0186x over previous
//
#include <hip/hip_runtime.h>
#include <stdint.h>

// AggFeatureModel, FUSED single-pass (T==2048 path), r10:
//  r9 + occupancy push: LDS 42->33.3KB so 4 blocks/CU fit (was 3), with
//  __launch_bounds__(512,8) for 32 resident waves/CU. part[] table merged
//  deterministically (half0 wave stores, barrier, half1 wave +=) instead of
//  dual tables -- halves part LDS and kills the dual-read in the epilogue.
//  Phase A key packing via v_perm (3 ops/stream vs 6).
// Fallback: proven r6 bf16 single-pass kernel for T != 2048.

#define NCOL 456
static constexpr float EPS = 1e-9f;

typedef __bf16 bf16x8 __attribute__((ext_vector_type(8)));
typedef float  f32x4  __attribute__((ext_vector_type(4)));
typedef int    i32x8  __attribute__((ext_vector_type(8)));
typedef unsigned int u32x4 __attribute__((ext_vector_type(4)));
typedef short  s16x2  __attribute__((ext_vector_type(2)));

__device__ __forceinline__ uint32_t hw_eqmask(uint32_t h) {
    // halfword SWAR eq-zero (legacy kernel)
    const uint32_t s = 0x80008000u - h;
    const s16x2 m = __builtin_bit_cast(s16x2, s) >> 15;
    return __builtin_bit_cast(uint32_t, m);
}

__device__ __forceinline__ uint32_t pack_lobytes(int4 m) {
    // [w0,z0,y0,x0] from the low bytes of 4 ints: 3 v_perm
    const uint32_t p01 = __builtin_amdgcn_perm((uint32_t)m.y, (uint32_t)m.x, 0x00000400u);
    const uint32_t p23 = __builtin_amdgcn_perm((uint32_t)m.w, (uint32_t)m.z, 0x00000400u);
    return __builtin_amdgcn_perm(p23, p01, 0x05040100u);
}

// ---------------- fused kernel (T == 2048) ----------------
__global__ __launch_bounds__(512, 8) void agg_fused(
    const float4* __restrict__ a4,
    const int4* __restrict__ m4,
    const int4* __restrict__ t4,
    const int* __restrict__ seq_lens,
    float* __restrict__ out, int B)
{
    const int tid  = threadIdx.x;
    const int lane = tid & 63;
    const int wv   = tid >> 6;           // 0..7

    __shared__ uint32_t lv[2048];        // fp8 bytes, 4 rows x 2048
    __shared__ uint32_t lm[2048];        // mcc key bytes
    __shared__ uint32_t lt[2048];        // tr key bytes
    __shared__ float part[4][3][176];    // merged per-row stat tables (8.4 KB)
    __shared__ float scw[4][8][2];       // [row][wave]{s,ss}

    // ---- phase A: stage + convert + exact f32 row partials ----
    const size_t base4 = (size_t)blockIdx.x * 2048;   // float4 units
#pragma unroll
    for (int j = 0; j < 4; ++j) {        // round j == local row j
        const size_t gi = base4 + (size_t)j * 512 + tid;
        const float4 a = a4[gi];
        const int4   m = m4[gi];
        const int4   t = t4[gi];

        uint32_t w = __builtin_amdgcn_cvt_pk_fp8_f32(a.x, a.y, 0u, false);
        w = __builtin_amdgcn_cvt_pk_fp8_f32(a.z, a.w, w, true);
        lv[j * 512 + tid] = w;
        lm[j * 512 + tid] = pack_lobytes(m);
        lt[j * 512 + tid] = pack_lobytes(t);

        float s = (a.x + a.y) + (a.z + a.w);
        float q = fmaf(a.x, a.x, fmaf(a.y, a.y, fmaf(a.z, a.z, a.w * a.w)));
#pragma unroll
        for (int off = 32; off; off >>= 1) {
            s += __shfl_xor(s, off, 64);
            q += __shfl_xor(q, off, 64);
        }
        if (lane == 0) { scw[j][wv][0] = s; scw[j][wv][1] = q; }
    }
    __syncthreads();

    // ---- phase B: MX-fp8 K=128 MFMA histogram from LDS ----
    const int rl   = wv >> 1;            // local row
    const int half = wv & 1;             // half of T axis
    const int row  = blockIdx.x * 4 + rl;
    const int n    = lane & 15;
    const int grp  = lane >> 4;
    const bool istr = (grp >= 2);
    const int ntc  = istr ? ((n - 7) & 15) : n;
    const uint32_t patB = (uint32_t)(((ntc << 4) | n) * 0x01010101u);

    const int bb = rl * 2048 + half * 1024 + ((grp & 1) << 5);
    const uint8_t* pv = (const uint8_t*)lv + bb;
    const uint8_t* pk = (const uint8_t*)(istr ? lt : lm) + bb;

    f32x4 accC = {0.f,0.f,0.f,0.f};
    f32x4 accS = {0.f,0.f,0.f,0.f};
    f32x4 accQ = {0.f,0.f,0.f,0.f};

#pragma unroll 2
    for (int st = 0; st < 16; ++st) {    // 64 elems/step over half-row
        const int off = st << 6;
        const uint4 v0 = *reinterpret_cast<const uint4*>(pv + off);
        const uint4 v1 = *reinterpret_cast<const uint4*>(pv + off + 16);
        const uint4 k0 = *reinterpret_cast<const uint4*>(pk + off);
        const uint4 k1 = *reinterpret_cast<const uint4*>(pk + off + 16);

        i32x8 fA1, fAa, fB1, fBa;
#define DOW(j, kw, vw) { \
        const uint32_t kx = (kw) ^ patB; \
        const uint32_t hu = kx & 0x0f0f0f0fu; \
        const uint32_t mu = (((0x80808080u - hu) & 0x80808080u) >> 7) * 255u; \
        const uint32_t ht = (kx >> 4) & 0x0f0f0f0fu; \
        const uint32_t mt = (((0x80808080u - ht) & 0x80808080u) >> 7) * 255u; \
        fA1[j] = (int)(mt & 0x38383838u);  /* one-hot(t) * 1.0 (e4m3) */ \
        fAa[j] = (int)(mt & (vw)); \
        fB1[j] = (int)(mu & 0x38383838u); \
        fBa[j] = (int)(mu & (vw)); }
        DOW(0, k0.x, v0.x) DOW(1, k0.y, v0.y) DOW(2, k0.z, v0.z) DOW(3, k0.w, v0.w)
        DOW(4, k1.x, v1.x) DOW(5, k1.y, v1.y) DOW(6, k1.z, v1.z) DOW(7, k1.w, v1.w)
#undef DOW

        accC = __builtin_amdgcn_mfma_scale_f32_16x16x128_f8f6f4(
                   fA1, fB1, accC, 0, 0, 0, 0x7f7f7f7f, 0, 0x7f7f7f7f);
        accS = __builtin_amdgcn_mfma_scale_f32_16x16x128_f8f6f4(
                   fA1, fBa, accS, 0, 0, 0, 0x7f7f7f7f, 0, 0x7f7f7f7f);
        accQ = __builtin_amdgcn_mfma_scale_f32_16x16x128_f8f6f4(
                   fAa, fBa, accQ, 0, 0, 0, 0x7f7f7f7f, 0, 0x7f7f7f7f);
    }

    // ---- deterministic two-step merge of half tables ----
    // D layout: col = lane&15, row = grp*4 + reg (r8-proven).
    // half0 wave STOREs all 176 slots/stat; barrier; half1 wave ADDs.
    float* my = &part[rl][0][0];
    if (!half) {
#pragma unroll
        for (int r = 0; r < 4; ++r) {
            const int rr = grp * 4 + r;
            int addr = -1;
            if (rr <= 6)       addr = rr * 16 + n;
            else if (rr <= 10) addr = 112 + (rr - 7) * 16 + n;
            if (addr >= 0) {
                my[addr]       = accC[r];
                my[176 + addr] = accS[r];
                my[352 + addr] = accQ[r];
            }
        }
    }
    __syncthreads();
    if (half) {
#pragma unroll
        for (int r = 0; r < 4; ++r) {
            const int rr = grp * 4 + r;
            int addr = -1;
            if (rr <= 6)       addr = rr * 16 + n;
            else if (rr <= 10) addr = 112 + (rr - 7) * 16 + n;
            if (addr >= 0) {
                my[addr]       += accC[r];
                my[176 + addr] += accS[r];
                my[352 + addr] += accQ[r];
            }
        }
    }
    __syncthreads();

    auto TB = [&](int s, int c) -> float { return part[rl][s][c]; };

    int dm = 0, dt = 0;
    if (half) {
        for (int c0 = 0; c0 < 160; c0 += 64) {
            const int c = c0 + lane;
            bool pos = false;
            if (c >= 1 && c < 100)        pos = TB(0, c) > 0.f;
            else if (c >= 101 && c < 150) pos = TB(0, 112 + (c - 100)) > 0.f;
            dm += __popcll(__ballot(pos && c < 100));
            dt += __popcll(__ballot(pos && c >= 100));
        }
    }

    float s_tot = 0.f, ss_tot = 0.f;
#pragma unroll
    for (int w = 0; w < 8; ++w) {
        s_tot  += scw[rl][w][0];
        ss_tot += scw[rl][w][1];
    }
    const float sl = (float)seq_lens[row];
    float* orow = out + (size_t)row * NCOL;

    for (int cc = lane; cc < 228; cc += 64) {
        const int col = half * 228 + cc;
        float v;
        if (col == 0)      v = sl;
        else if (col == 1) v = s_tot;
        else if (col == 2) v = s_tot / (sl + EPS);
        else if (col == 3) {
            float a = fmaxf(ss_tot - s_tot * s_tot / (sl + EPS), 0.f);
            v = sqrtf(a / (fmaxf(sl - 1.f, 0.f) + EPS));
        }
        else if (col == 454) v = (float)dm;
        else if (col == 455) v = (float)dt;
        else {
            int base, C, toff;
            if (col < 304) { base = 4;   C = 100; toff = 0;   }
            else           { base = 304; C = 50;  toff = 112; }
            const int rel   = col - base;
            const int which = rel / C;
            const int c     = rel - which * C;
            const float cnt = (c > 0) ? TB(0, toff + c) : 0.f;
            const float sc  = TB(1, toff + c);
            const float ssc = TB(2, toff + c);
            if (which == 0)      v = cnt;
            else if (which == 1) v = sc / (cnt + EPS);
            else {
                float a = fmaxf(ssc - sc * sc / (cnt + EPS), 0.f);
                v = sqrtf(a / (fmaxf(cnt - 1.f, 0.f) + EPS));
            }
        }
        orow[col] = v;
    }
}

// ---------------- fallback: proven r6 single-pass bf16 kernel ----------------
__global__ __launch_bounds__(512, 8) void agg2d_legacy(
    const float* __restrict__ amount,
    const int* __restrict__ mcc,
    const int* __restrict__ tr,
    const int* __restrict__ seq_lens,
    float* __restrict__ out, int T, int B)
{
    const int lane = threadIdx.x & 63;
    const int wv   = threadIdx.x >> 6;
    const int rl   = wv >> 1;
    const int half = wv & 1;
    const int row  = blockIdx.x * 4 + rl;
    const int n    = lane & 15;
    const int grp  = lane >> 4;
    const bool istr = (grp >= 2);
    const int ntc  = istr ? ((n - 7) & 15) : n;
    const uint32_t xorpat = (uint32_t)(((ntc << 4) | n) * 0x00010001u);
    const int roff = (grp & 1) * 8;

    __shared__ float part[4][2][3][176];
    __shared__ float scal[4][2][2];

    const int hb = half * (T >> 1);
    const float* pa = amount + (size_t)row * T + hb + roff;
    const int*   pk = (istr ? tr : mcc) + (size_t)row * T + hb + roff;

    f32x4 accC = {0.f,0.f,0.f,0.f};
    f32x4 accS = {0.f,0.f,0.f,0.f};
    f32x4 accQ = {0.f,0.f,0.f,0.f};

    const int nstep = T >> 5;
#pragma unroll 2
    for (int st = 0; st < nstep; ++st) {
        const int base = st << 4;
        const float4 a0 = *reinterpret_cast<const float4*>(pa + base);
        const float4 a1 = *reinterpret_cast<const float4*>(pa + base + 4);
        const int4   k0 = *reinterpret_cast<const int4*>(pk + base);
        const int4   k1 = *reinterpret_cast<const int4*>(pk + base + 4);

        const float av[8] = {a0.x,a0.y,a0.z,a0.w,a1.x,a1.y,a1.z,a1.w};
        const uint32_t kv[8] = {(uint32_t)k0.x,(uint32_t)k0.y,(uint32_t)k0.z,(uint32_t)k0.w,
                                (uint32_t)k1.x,(uint32_t)k1.y,(uint32_t)k1.z,(uint32_t)k1.w};

        u32x4 wA1, wAa, wB1, wBa;
#pragma unroll
        for (int i = 0; i < 4; ++i) {
            const uint32_t kpk = __builtin_amdgcn_perm(kv[2*i+1], kv[2*i], 0x05040100u);
            const uint32_t kx  = kpk ^ xorpat;
            const uint32_t mu  = hw_eqmask(kx & 0x000f000fu);
            const uint32_t mt  = hw_eqmask((kx >> 4) & 0x000f000fu);
            const uint32_t apk = __builtin_amdgcn_perm(
                __float_as_uint(av[2*i+1]), __float_as_uint(av[2*i]), 0x07060302u);
            wA1[i] = mt & 0x3f803f80u;
            wAa[i] = mt & apk;
            wB1[i] = mu & 0x3f803f80u;
            wBa[i] = mu & apk;
        }
        const bf16x8 fA1 = __builtin_bit_cast(bf16x8, wA1);
        const bf16x8 fAa = __builtin_bit_cast(bf16x8, wAa);
        const bf16x8 fB1 = __builtin_bit_cast(bf16x8, wB1);
        const bf16x8 fBa = __builtin_bit_cast(bf16x8, wBa);

        accC = __builtin_amdgcn_mfma_f32_16x16x32_bf16(fA1, fB1, accC, 0, 0, 0);
        accS = __builtin_amdgcn_mfma_f32_16x16x32_bf16(fA1, fBa, accS, 0, 0, 0);
        accQ = __builtin_amdgcn_mfma_f32_16x16x32_bf16(fAa, fBa, accQ, 0, 0, 0);
    }

    {
        float* my = &part[rl][half][0][0];
#pragma unroll
        for (int r = 0; r < 4; ++r) {
            const int rr = grp * 4 + r;
            int addr = -1;
            if (rr <= 6)       addr = rr * 16 + n;
            else if (rr <= 10) addr = 112 + (rr - 7) * 16 + n;
            if (addr >= 0) {
                my[addr]       = accC[r];
                my[176 + addr] = accS[r];
                my[352 + addr] = accQ[r];
            }
        }
    }
    float sS = 0.f, sQ = 0.f;
    if (grp == 0) {
        sS = accS[0] + accS[1] + accS[2] + accS[3];
        sQ = accQ[0] + accQ[1] + accQ[2] + accQ[3];
    } else if (grp == 1) {
        sS = accS[0] + accS[1] + accS[2];
        sQ = accQ[0] + accQ[1] + accQ[2];
    }
#pragma unroll
    for (int off = 32; off; off >>= 1) {
        sS += __shfl_xor(sS, off, 64);
        sQ += __shfl_xor(sQ, off, 64);
    }
    if (lane == 0) { scal[rl][half][0] = sS; scal[rl][half][1] = sQ; }
    __syncthreads();

    auto TB = [&](int s, int c) -> float {
        return part[rl][0][s][c] + part[rl][1][s][c];
    };

    int dm = 0, dt = 0;
    if (half) {
        for (int c0 = 0; c0 < 160; c0 += 64) {
            const int c = c0 + lane;
            bool pos = false;
            if (c >= 1 && c < 100)        pos = TB(0, c) > 0.f;
            else if (c >= 101 && c < 150) pos = TB(0, 112 + (c - 100)) > 0.f;
            dm += __popcll(__ballot(pos && c < 100));
            dt += __popcll(__ballot(pos && c >= 100));
        }
    }

    const float sl     = (float)seq_lens[row];
    const float s_tot  = scal[rl][0][0] + scal[rl][1][0];
    const float ss_tot = scal[rl][0][1] + scal[rl][1][1];
    float* orow = out + (size_t)row * NCOL;

    for (int cc = lane; cc < 228; cc += 64) {
        const int col = half * 228 + cc;
        float v;
        if (col == 0)      v = sl;
        else if (col == 1) v = s_tot;
        else if (col == 2) v = s_tot / (sl + EPS);
        else if (col == 3) {
            float a = fmaxf(ss_tot - s_tot * s_tot / (sl + EPS), 0.f);
            v = sqrtf(a / (fmaxf(sl - 1.f, 0.f) + EPS));
        }
        else if (col == 454) v = (float)dm;
        else if (col == 455) v = (float)dt;
        else {
            int base, C, toff;
            if (col < 304) { base = 4;   C = 100; toff = 0;   }
            else           { base = 304; C = 50;  toff = 112; }
            const int rel   = col - base;
            const int which = rel / C;
            const int c     = rel - which * C;
            const float cnt = (c > 0) ? TB(0, toff + c) : 0.f;
            const float sc  = TB(1, toff + c);
            const float ssc = TB(2, toff + c);
            if (which == 0)      v = cnt;
            else if (which == 1) v = sc / (cnt + EPS);
            else {
                float a = fmaxf(ssc - sc * sc / (cnt + EPS), 0.f);
                v = sqrtf(a / (fmaxf(cnt - 1.f, 0.f) + EPS));
            }
        }
        orow[col] = v;
    }
}

extern "C" void kernel_launch(void* const* d_in, const int* in_sizes, int n_in,
                              void* d_out, int out_size, void* d_ws, size_t ws_size,
                              hipStream_t stream) {
    const float* amount   = (const float*)d_in[0];
    const int*   mcc      = (const int*)d_in[1];
    const int*   tr_type  = (const int*)d_in[2];
    const int*   seq_lens = (const int*)d_in[3];
    float*       out      = (float*)d_out;

    const int B = in_sizes[3];            // 4096
    const int T = in_sizes[0] / B;        // 2048

    if (T == 2048 && (B % 4) == 0) {
        agg_fused<<<B / 4, 512, 0, stream>>>(
            (const float4*)amount, (const int4*)mcc, (const int4*)tr_type,
            seq_lens, out, B);
    } else {
        agg2d_legacy<<<B / 4, 512, 0, stream>>>(amount, mcc, tr_type, seq_lens, out, T, B);
    }
}